// Round 2
// baseline (549.877 us; speedup 1.0000x reference)
//
#include <hip/hip_runtime.h>

#define GRIDSZ 64
#define NBATCH 16
#define NPTS   500000
#define NTRIP  (NPTS / 4)          // 125000 triples-of-float4 (4 points each)
#define FLOATS_PER_BATCH (NPTS * 3)
#define BINS_PER_BATCH (GRIDSZ * GRIDSZ * GRIDSZ)

// Monotonic float<->uint encoding: order-preserving, so uint atomicMin/Max
// computes float min/max exactly.
__device__ __forceinline__ unsigned encf(float f) {
    unsigned u = __float_as_uint(f);
    return (u & 0x80000000u) ? ~u : (u | 0x80000000u);
}
__device__ __forceinline__ float decf(unsigned u) {
    return __uint_as_float((u & 0x80000000u) ? (u ^ 0x80000000u) : ~u);
}

__global__ void init_ws_kernel(unsigned* __restrict__ ws) {
    int t = threadIdx.x;
    if (t < NBATCH * 6) {
        // slots [b*6+0..2] = encoded min (init to +inf encoding = 0xFFFFFFFF)
        // slots [b*6+3..5] = encoded max (init to -inf encoding = 0x00000000)
        ws[t] = ((t % 6) < 3) ? 0xFFFFFFFFu : 0u;
    }
}

__global__ void minmax_kernel(const float* __restrict__ pts,
                              unsigned* __restrict__ ws) {
    const int b = blockIdx.y;
    const float4* __restrict__ p4 =
        reinterpret_cast<const float4*>(pts + (size_t)b * FLOATS_PER_BATCH);

    float mn[3] = {INFINITY, INFINITY, INFINITY};
    float mx[3] = {-INFINITY, -INFINITY, -INFINITY};

    const int stride = gridDim.x * blockDim.x;
    for (int i = blockIdx.x * blockDim.x + threadIdx.x; i < NTRIP; i += stride) {
        float4 A = p4[3 * i + 0];
        float4 B = p4[3 * i + 1];
        float4 C = p4[3 * i + 2];
        // 4 points: (A.x,A.y,A.z) (A.w,B.x,B.y) (B.z,B.w,C.x) (C.y,C.z,C.w)
        float xs[4] = {A.x, A.w, B.z, C.y};
        float ys[4] = {A.y, B.x, B.w, C.z};
        float zs[4] = {A.z, B.y, C.x, C.w};
#pragma unroll
        for (int j = 0; j < 4; ++j) {
            mn[0] = fminf(mn[0], xs[j]); mx[0] = fmaxf(mx[0], xs[j]);
            mn[1] = fminf(mn[1], ys[j]); mx[1] = fmaxf(mx[1], ys[j]);
            mn[2] = fminf(mn[2], zs[j]); mx[2] = fmaxf(mx[2], zs[j]);
        }
    }

    // wave-64 butterfly reduce
#pragma unroll
    for (int m = 1; m < 64; m <<= 1) {
#pragma unroll
        for (int c = 0; c < 3; ++c) {
            mn[c] = fminf(mn[c], __shfl_xor(mn[c], m));
            mx[c] = fmaxf(mx[c], __shfl_xor(mx[c], m));
        }
    }
    if ((threadIdx.x & 63) == 0) {
#pragma unroll
        for (int c = 0; c < 3; ++c) {
            atomicMin(&ws[b * 6 + c],     encf(mn[c]));
            atomicMax(&ws[b * 6 + 3 + c], encf(mx[c]));
        }
    }
}

__global__ void hist_kernel(const float* __restrict__ pts,
                            const unsigned* __restrict__ ws,
                            float* __restrict__ out) {
    const int b = blockIdx.y;
    __shared__ float smn[3], sden[3];
    if (threadIdx.x < 3) {
        float mn = decf(ws[b * 6 + threadIdx.x]);
        float mx = decf(ws[b * 6 + 3 + threadIdx.x]);
        smn[threadIdx.x]  = mn;
        sden[threadIdx.x] = (mx - mn) + 1e-6f;   // matches ref: (pmax-pmin)+EPS
    }
    __syncthreads();
    const float mn0 = smn[0], mn1 = smn[1], mn2 = smn[2];
    const float d0 = sden[0], d1 = sden[1], d2 = sden[2];

    const float4* __restrict__ p4 =
        reinterpret_cast<const float4*>(pts + (size_t)b * FLOATS_PER_BATCH);
    float* __restrict__ outb = out + (size_t)b * BINS_PER_BATCH;

    const int stride = gridDim.x * blockDim.x;
    for (int i = blockIdx.x * blockDim.x + threadIdx.x; i < NTRIP; i += stride) {
        float4 A = p4[3 * i + 0];
        float4 B = p4[3 * i + 1];
        float4 C = p4[3 * i + 2];
        float xs[4] = {A.x, A.w, B.z, C.y};
        float ys[4] = {A.y, B.x, B.w, C.z};
        float zs[4] = {A.z, B.y, C.x, C.w};
#pragma unroll
        for (int j = 0; j < 4; ++j) {
            // Replicate reference float op sequence exactly (IEEE div, no rcp):
            // t = (p - mn) / den;  norm = t*2 - 1;  idx = floor((norm+1)*32)
            float tx = (xs[j] - mn0) / d0;
            float ty = (ys[j] - mn1) / d1;
            float tz = (zs[j] - mn2) / d2;
            float nx = tx * 2.0f - 1.0f;
            float ny = ty * 2.0f - 1.0f;
            float nz = tz * 2.0f - 1.0f;
            bool ok = (nx >= -1.0f) & (nx <= 1.0f) &
                      (ny >= -1.0f) & (ny <= 1.0f) &
                      (nz >= -1.0f) & (nz <= 1.0f);
            int ix = (int)floorf((nx + 1.0f) * 32.0f);
            int iy = (int)floorf((ny + 1.0f) * 32.0f);
            int iz = (int)floorf((nz + 1.0f) * 32.0f);
            ix = min(max(ix, 0), GRIDSZ - 1);
            iy = min(max(iy, 0), GRIDSZ - 1);
            iz = min(max(iz, 0), GRIDSZ - 1);
            if (ok) {
                int bin = (ix * GRIDSZ + iy) * GRIDSZ + iz;
                atomicAdd(&outb[bin], 1.0f);
            }
        }
    }
}

extern "C" void kernel_launch(void* const* d_in, const int* in_sizes, int n_in,
                              void* d_out, int out_size, void* d_ws, size_t ws_size,
                              hipStream_t stream) {
    const float* pts = (const float*)d_in[0];
    float* out = (float*)d_out;
    unsigned* ws = (unsigned*)d_ws;

    // Output is accumulated atomically -> zero it every call (capture-safe).
    hipMemsetAsync(d_out, 0, (size_t)out_size * sizeof(float), stream);
    init_ws_kernel<<<1, 128, 0, stream>>>(ws);
    minmax_kernel<<<dim3(64, NBATCH), 256, 0, stream>>>(pts, ws);
    hist_kernel<<<dim3(128, NBATCH), 256, 0, stream>>>(pts, ws, out);
}

// Round 3
// 279.482 us; speedup vs baseline: 1.9675x; 1.9675x over previous
//
#include <hip/hip_runtime.h>

#define GRIDSZ 64
#define NBATCH 16
#define NPTS   500000
#define NTRIP  (NPTS / 4)          // 125000 triples-of-float4 (4 points each)
#define FLOATS_PER_BATCH (NPTS * 3)
#define BINS_PER_BATCH (GRIDSZ * GRIDSZ * GRIDSZ)

// LDS-privatized histogram parameters
#define CHUNKS   32                 // blocks per batch in hist pass
#define HBLOCKS  (NBATCH * CHUNKS)  // 512 blocks (2 per CU with 64KB LDS)
#define HTHREADS 512
#define R0  16                      // central region = bins [16,48) per dim
#define RSZ 32
#define WORDS (RSZ * RSZ * (RSZ / 2))  // 16384 packed u16-pair words = 64KB
#define PART_OFF_U32 256            // partials start at byte 1024 of ws

// Monotonic float<->uint encoding: order-preserving, so uint atomicMin/Max
// computes float min/max exactly.
__device__ __forceinline__ unsigned encf(float f) {
    unsigned u = __float_as_uint(f);
    return (u & 0x80000000u) ? ~u : (u | 0x80000000u);
}
__device__ __forceinline__ float decf(unsigned u) {
    return __uint_as_float((u & 0x80000000u) ? (u ^ 0x80000000u) : ~u);
}

__global__ void init_ws_kernel(unsigned* __restrict__ ws) {
    int t = threadIdx.x;
    if (t < NBATCH * 6) {
        ws[t] = ((t % 6) < 3) ? 0xFFFFFFFFu : 0u;  // min slots=+inf enc, max slots=-inf enc
    }
}

__global__ void minmax_kernel(const float* __restrict__ pts,
                              unsigned* __restrict__ ws) {
    const int b = blockIdx.y;
    const float4* __restrict__ p4 =
        reinterpret_cast<const float4*>(pts + (size_t)b * FLOATS_PER_BATCH);

    float mn[3] = {INFINITY, INFINITY, INFINITY};
    float mx[3] = {-INFINITY, -INFINITY, -INFINITY};

    const int stride = gridDim.x * blockDim.x;
    for (int i = blockIdx.x * blockDim.x + threadIdx.x; i < NTRIP; i += stride) {
        float4 A = p4[3 * i + 0];
        float4 B = p4[3 * i + 1];
        float4 C = p4[3 * i + 2];
        float xs[4] = {A.x, A.w, B.z, C.y};
        float ys[4] = {A.y, B.x, B.w, C.z};
        float zs[4] = {A.z, B.y, C.x, C.w};
#pragma unroll
        for (int j = 0; j < 4; ++j) {
            mn[0] = fminf(mn[0], xs[j]); mx[0] = fmaxf(mx[0], xs[j]);
            mn[1] = fminf(mn[1], ys[j]); mx[1] = fmaxf(mx[1], ys[j]);
            mn[2] = fminf(mn[2], zs[j]); mx[2] = fmaxf(mx[2], zs[j]);
        }
    }
#pragma unroll
    for (int m = 1; m < 64; m <<= 1) {
#pragma unroll
        for (int c = 0; c < 3; ++c) {
            mn[c] = fminf(mn[c], __shfl_xor(mn[c], m));
            mx[c] = fmaxf(mx[c], __shfl_xor(mx[c], m));
        }
    }
    if ((threadIdx.x & 63) == 0) {
#pragma unroll
        for (int c = 0; c < 3; ++c) {
            atomicMin(&ws[b * 6 + c],     encf(mn[c]));
            atomicMax(&ws[b * 6 + 3 + c], encf(mx[c]));
        }
    }
}

// Shared binning math — EXACTLY the arithmetic of the passing round-2 kernel.
__device__ __forceinline__ void bin_point(float x, float y, float z,
                                          float mn0, float mn1, float mn2,
                                          float d0, float d1, float d2,
                                          bool& ok, int& ix, int& iy, int& iz) {
    float tx = (x - mn0) / d0;
    float ty = (y - mn1) / d1;
    float tz = (z - mn2) / d2;
    float nx = tx * 2.0f - 1.0f;
    float ny = ty * 2.0f - 1.0f;
    float nz = tz * 2.0f - 1.0f;
    ok = (nx >= -1.0f) & (nx <= 1.0f) &
         (ny >= -1.0f) & (ny <= 1.0f) &
         (nz >= -1.0f) & (nz <= 1.0f);
    ix = (int)floorf((nx + 1.0f) * 32.0f);
    iy = (int)floorf((ny + 1.0f) * 32.0f);
    iz = (int)floorf((nz + 1.0f) * 32.0f);
    ix = min(max(ix, 0), GRIDSZ - 1);
    iy = min(max(iy, 0), GRIDSZ - 1);
    iz = min(max(iz, 0), GRIDSZ - 1);
}

// LDS-privatized hist: central 32^3 bins counted in LDS (packed 2xu16),
// outliers via global atomics, partials flushed to ws with plain stores.
__global__ __launch_bounds__(HTHREADS) void hist_lds_kernel(
        const float* __restrict__ pts, const unsigned* __restrict__ ws,
        unsigned* __restrict__ partials, float* __restrict__ out) {
    __shared__ unsigned cnt[WORDS];          // 64 KB
    const int bx = blockIdx.x;
    const int b = bx >> 5;                   // batch
    const int chunk = bx & (CHUNKS - 1);

    for (int w = threadIdx.x; w < WORDS; w += HTHREADS) cnt[w] = 0u;

    __shared__ float smn[3], sden[3];
    if (threadIdx.x < 3) {
        float mn = decf(ws[b * 6 + threadIdx.x]);
        float mx = decf(ws[b * 6 + 3 + threadIdx.x]);
        smn[threadIdx.x]  = mn;
        sden[threadIdx.x] = (mx - mn) + 1e-6f;
    }
    __syncthreads();
    const float mn0 = smn[0], mn1 = smn[1], mn2 = smn[2];
    const float d0 = sden[0], d1 = sden[1], d2 = sden[2];

    const float4* __restrict__ p4 =
        reinterpret_cast<const float4*>(pts + (size_t)b * FLOATS_PER_BATCH);
    float* __restrict__ outb = out + (size_t)b * BINS_PER_BATCH;

    for (int i = chunk * HTHREADS + threadIdx.x; i < NTRIP; i += CHUNKS * HTHREADS) {
        float4 A = p4[3 * i + 0];
        float4 B = p4[3 * i + 1];
        float4 C = p4[3 * i + 2];
        float xs[4] = {A.x, A.w, B.z, C.y};
        float ys[4] = {A.y, B.x, B.w, C.z};
        float zs[4] = {A.z, B.y, C.x, C.w};
#pragma unroll
        for (int j = 0; j < 4; ++j) {
            bool ok; int ix, iy, iz;
            bin_point(xs[j], ys[j], zs[j], mn0, mn1, mn2, d0, d1, d2, ok, ix, iy, iz);
            if (ok) {
                unsigned rx = (unsigned)(ix - R0), ry = (unsigned)(iy - R0), rz = (unsigned)(iz - R0);
                if ((rx < RSZ) & (ry < RSZ) & (rz < RSZ)) {
                    unsigned word = (rx * RSZ + ry) * (RSZ / 2) + (rz >> 1);
                    atomicAdd(&cnt[word], (rz & 1u) ? 0x10000u : 1u);
                } else {
                    int bin = (ix * GRIDSZ + iy) * GRIDSZ + iz;
                    atomicAdd(&outb[bin], 1.0f);
                }
            }
        }
    }
    __syncthreads();

    unsigned* __restrict__ slot = partials + (size_t)bx * WORDS;
    for (int w = threadIdx.x; w < WORDS; w += HTHREADS) slot[w] = cnt[w];
}

// Sum the 32 per-chunk partials per batch; plain stores (outliers never touch
// central bins, so no read-modify-write needed; out was memset to 0).
__global__ void reduce_kernel(const unsigned* __restrict__ partials,
                              float* __restrict__ out) {
    const int b = blockIdx.y;
    const int w = blockIdx.x * 256 + threadIdx.x;   // [0, WORDS)
    const unsigned* __restrict__ base = partials + (size_t)b * CHUNKS * WORDS;
    unsigned s0 = 0, s1 = 0;
#pragma unroll 4
    for (int c = 0; c < CHUNKS; ++c) {
        unsigned v = base[(size_t)c * WORDS + w];
        s0 += v & 0xFFFFu;
        s1 += v >> 16;
    }
    int ix = R0 + (w >> 9);          // w / (RSZ * RSZ/2)
    int iy = R0 + ((w >> 4) & (RSZ - 1));
    int iz = R0 + ((w & (RSZ / 2 - 1)) << 1);
    float* __restrict__ outb = out + (size_t)b * BINS_PER_BATCH;
    int bin = (ix * GRIDSZ + iy) * GRIDSZ + iz;
    outb[bin]     = (float)s0;
    outb[bin + 1] = (float)s1;
}

// Fallback (ws too small): the round-2 direct-atomic kernel (correct, slower).
__global__ void hist_kernel(const float* __restrict__ pts,
                            const unsigned* __restrict__ ws,
                            float* __restrict__ out) {
    const int b = blockIdx.y;
    __shared__ float smn[3], sden[3];
    if (threadIdx.x < 3) {
        float mn = decf(ws[b * 6 + threadIdx.x]);
        float mx = decf(ws[b * 6 + 3 + threadIdx.x]);
        smn[threadIdx.x]  = mn;
        sden[threadIdx.x] = (mx - mn) + 1e-6f;
    }
    __syncthreads();
    const float mn0 = smn[0], mn1 = smn[1], mn2 = smn[2];
    const float d0 = sden[0], d1 = sden[1], d2 = sden[2];

    const float4* __restrict__ p4 =
        reinterpret_cast<const float4*>(pts + (size_t)b * FLOATS_PER_BATCH);
    float* __restrict__ outb = out + (size_t)b * BINS_PER_BATCH;

    const int stride = gridDim.x * blockDim.x;
    for (int i = blockIdx.x * blockDim.x + threadIdx.x; i < NTRIP; i += stride) {
        float4 A = p4[3 * i + 0];
        float4 B = p4[3 * i + 1];
        float4 C = p4[3 * i + 2];
        float xs[4] = {A.x, A.w, B.z, C.y};
        float ys[4] = {A.y, B.x, B.w, C.z};
        float zs[4] = {A.z, B.y, C.x, C.w};
#pragma unroll
        for (int j = 0; j < 4; ++j) {
            bool ok; int ix, iy, iz;
            bin_point(xs[j], ys[j], zs[j], mn0, mn1, mn2, d0, d1, d2, ok, ix, iy, iz);
            if (ok) {
                int bin = (ix * GRIDSZ + iy) * GRIDSZ + iz;
                atomicAdd(&outb[bin], 1.0f);
            }
        }
    }
}

extern "C" void kernel_launch(void* const* d_in, const int* in_sizes, int n_in,
                              void* d_out, int out_size, void* d_ws, size_t ws_size,
                              hipStream_t stream) {
    const float* pts = (const float*)d_in[0];
    float* out = (float*)d_out;
    unsigned* ws = (unsigned*)d_ws;

    const size_t need = (size_t)PART_OFF_U32 * 4 + (size_t)HBLOCKS * WORDS * 4;

    hipMemsetAsync(d_out, 0, (size_t)out_size * sizeof(float), stream);
    init_ws_kernel<<<1, 128, 0, stream>>>(ws);
    minmax_kernel<<<dim3(128, NBATCH), 256, 0, stream>>>(pts, ws);

    if (ws_size >= need) {
        unsigned* partials = ws + PART_OFF_U32;
        hist_lds_kernel<<<HBLOCKS, HTHREADS, 0, stream>>>(pts, ws, partials, out);
        reduce_kernel<<<dim3(WORDS / 256, NBATCH), 256, 0, stream>>>(partials, out);
    } else {
        hist_kernel<<<dim3(128, NBATCH), 256, 0, stream>>>(pts, ws, out);
    }
}

// Round 7
// 76.190 us; speedup vs baseline: 7.2172x; 3.6682x over previous
//
#include <hip/hip_runtime.h>

#define GRIDSZ 64
#define NBATCH 16
#define NPTS   500000
#define NTRIP  (NPTS / 4)          // 125000 triples-of-float4 (4 points each)
#define FLOATS_PER_BATCH (NPTS * 3)
#define BINS_PER_BATCH (GRIDSZ * GRIDSZ * GRIDSZ)

// LDS-privatized histogram parameters
#define CHUNKS   32                 // blocks per batch in hist pass
#define HBLOCKS  (NBATCH * CHUNKS)  // 512 blocks (2 per CU with 64KB LDS)
#define HTHREADS 512
#define R0  16                      // central region = bins [16,48) per dim
#define RSZ 32
#define WORDS (RSZ * RSZ * (RSZ / 2))  // 16384 packed u16-pair words = 64KB

// minmax config
#define MMBLK 128                   // stage-1 blocks per batch

// ws layout (u32 units):
//  [0 .. 127]   finals: per batch 8 floats {mn0,mn1,mn2,den0,den1,den2,pad,pad}
//  [128..255]   pad
//  [256 .. ]    hist partials (HBLOCKS*WORDS u32) — ALSO reused (earlier in the
//               timeline) as minmax stage-1 partials (NBATCH*MMBLK*8 floats)
#define FINAL_OFF 0
#define PART_OFF_U32 256

__global__ __launch_bounds__(256) void minmax_stage1(
        const float* __restrict__ pts, float* __restrict__ partials) {
    const int b = blockIdx.y;
    const float4* __restrict__ p4 =
        reinterpret_cast<const float4*>(pts + (size_t)b * FLOATS_PER_BATCH);

    float mn[3] = {INFINITY, INFINITY, INFINITY};
    float mx[3] = {-INFINITY, -INFINITY, -INFINITY};

    const int stride = MMBLK * 256;
    for (int i = blockIdx.x * 256 + threadIdx.x; i < NTRIP; i += stride) {
        float4 A = p4[3 * i + 0];
        float4 B = p4[3 * i + 1];
        float4 C = p4[3 * i + 2];
        // 4 points: (A.x,A.y,A.z) (A.w,B.x,B.y) (B.z,B.w,C.x) (C.y,C.z,C.w)
        float xs[4] = {A.x, A.w, B.z, C.y};
        float ys[4] = {A.y, B.x, B.w, C.z};
        float zs[4] = {A.z, B.y, C.x, C.w};
#pragma unroll
        for (int j = 0; j < 4; ++j) {
            mn[0] = fminf(mn[0], xs[j]); mx[0] = fmaxf(mx[0], xs[j]);
            mn[1] = fminf(mn[1], ys[j]); mx[1] = fmaxf(mx[1], ys[j]);
            mn[2] = fminf(mn[2], zs[j]); mx[2] = fmaxf(mx[2], zs[j]);
        }
    }
    // wave-64 butterfly
#pragma unroll
    for (int m = 1; m < 64; m <<= 1) {
#pragma unroll
        for (int c = 0; c < 3; ++c) {
            mn[c] = fminf(mn[c], __shfl_xor(mn[c], m));
            mx[c] = fmaxf(mx[c], __shfl_xor(mx[c], m));
        }
    }
    // cross-wave via LDS (4 waves)
    __shared__ float red[4][6];
    const int wave = threadIdx.x >> 6;
    if ((threadIdx.x & 63) == 0) {
        red[wave][0] = mn[0]; red[wave][1] = mn[1]; red[wave][2] = mn[2];
        red[wave][3] = mx[0]; red[wave][4] = mx[1]; red[wave][5] = mx[2];
    }
    __syncthreads();
    if (threadIdx.x == 0) {
#pragma unroll
        for (int w = 1; w < 4; ++w) {
#pragma unroll
            for (int c = 0; c < 3; ++c) {
                red[0][c]     = fminf(red[0][c],     red[w][c]);
                red[0][3 + c] = fmaxf(red[0][3 + c], red[w][3 + c]);
            }
        }
        float4* slot = reinterpret_cast<float4*>(partials + (size_t)(b * MMBLK + blockIdx.x) * 8);
        slot[0] = make_float4(red[0][0], red[0][1], red[0][2], red[0][3]);
        slot[1] = make_float4(red[0][4], red[0][5], 0.0f, 0.0f);
    }
}

// One block per batch: reduce MMBLK partials -> finals {mn[3], den[3]}
__global__ __launch_bounds__(MMBLK) void minmax_stage2(
        const float* __restrict__ partials, float* __restrict__ finals) {
    const int b = blockIdx.x;
    const float4* slot = reinterpret_cast<const float4*>(
        partials + (size_t)(b * MMBLK + threadIdx.x) * 8);
    float4 a = slot[0];
    float4 c = slot[1];
    float mn[3] = {a.x, a.y, a.z};
    float mx[3] = {a.w, c.x, c.y};
#pragma unroll
    for (int m = 1; m < 64; m <<= 1) {
#pragma unroll
        for (int k = 0; k < 3; ++k) {
            mn[k] = fminf(mn[k], __shfl_xor(mn[k], m));
            mx[k] = fmaxf(mx[k], __shfl_xor(mx[k], m));
        }
    }
    __shared__ float red[2][6];
    const int wave = threadIdx.x >> 6;
    if ((threadIdx.x & 63) == 0) {
        red[wave][0] = mn[0]; red[wave][1] = mn[1]; red[wave][2] = mn[2];
        red[wave][3] = mx[0]; red[wave][4] = mx[1]; red[wave][5] = mx[2];
    }
    __syncthreads();
    if (threadIdx.x == 0) {
        float* f = finals + b * 8;
#pragma unroll
        for (int k = 0; k < 3; ++k) {
            float lo = fminf(red[0][k],     red[1][k]);
            float hi = fmaxf(red[0][3 + k], red[1][3 + k]);
            f[k]     = lo;
            f[3 + k] = (hi - lo) + 1e-6f;   // matches ref: (pmax-pmin)+EPS
        }
        f[6] = 0.0f; f[7] = 0.0f;
    }
}

// Shared binning math — EXACTLY the arithmetic of the passing rounds.
__device__ __forceinline__ void bin_point(float x, float y, float z,
                                          float mn0, float mn1, float mn2,
                                          float d0, float d1, float d2,
                                          bool& ok, int& ix, int& iy, int& iz) {
    float tx = (x - mn0) / d0;
    float ty = (y - mn1) / d1;
    float tz = (z - mn2) / d2;
    float nx = tx * 2.0f - 1.0f;
    float ny = ty * 2.0f - 1.0f;
    float nz = tz * 2.0f - 1.0f;
    ok = (nx >= -1.0f) & (nx <= 1.0f) &
         (ny >= -1.0f) & (ny <= 1.0f) &
         (nz >= -1.0f) & (nz <= 1.0f);
    ix = (int)floorf((nx + 1.0f) * 32.0f);
    iy = (int)floorf((ny + 1.0f) * 32.0f);
    iz = (int)floorf((nz + 1.0f) * 32.0f);
    ix = min(max(ix, 0), GRIDSZ - 1);
    iy = min(max(iy, 0), GRIDSZ - 1);
    iz = min(max(iz, 0), GRIDSZ - 1);
}

// LDS-privatized hist: central 32^3 bins counted in LDS (packed 2xu16),
// outliers via global atomics, partials flushed to ws with plain stores.
__global__ __launch_bounds__(HTHREADS) void hist_lds_kernel(
        const float* __restrict__ pts, const float* __restrict__ finals,
        unsigned* __restrict__ partials, float* __restrict__ out) {
    __shared__ unsigned cnt[WORDS];          // 64 KB
    const int bx = blockIdx.x;
    const int b = bx >> 5;                   // batch
    const int chunk = bx & (CHUNKS - 1);

    for (int w = threadIdx.x; w < WORDS; w += HTHREADS) cnt[w] = 0u;
    __syncthreads();

    const float mn0 = finals[b * 8 + 0], mn1 = finals[b * 8 + 1], mn2 = finals[b * 8 + 2];
    const float d0  = finals[b * 8 + 3], d1  = finals[b * 8 + 4], d2  = finals[b * 8 + 5];

    const float4* __restrict__ p4 =
        reinterpret_cast<const float4*>(pts + (size_t)b * FLOATS_PER_BATCH);
    float* __restrict__ outb = out + (size_t)b * BINS_PER_BATCH;

    for (int i = chunk * HTHREADS + threadIdx.x; i < NTRIP; i += CHUNKS * HTHREADS) {
        float4 A = p4[3 * i + 0];
        float4 B = p4[3 * i + 1];
        float4 C = p4[3 * i + 2];
        float xs[4] = {A.x, A.w, B.z, C.y};
        float ys[4] = {A.y, B.x, B.w, C.z};
        float zs[4] = {A.z, B.y, C.x, C.w};
#pragma unroll
        for (int j = 0; j < 4; ++j) {
            bool ok; int ix, iy, iz;
            bin_point(xs[j], ys[j], zs[j], mn0, mn1, mn2, d0, d1, d2, ok, ix, iy, iz);
            if (ok) {
                unsigned rx = (unsigned)(ix - R0), ry = (unsigned)(iy - R0), rz = (unsigned)(iz - R0);
                if ((rx < RSZ) & (ry < RSZ) & (rz < RSZ)) {
                    unsigned word = (rx * RSZ + ry) * (RSZ / 2) + (rz >> 1);
                    atomicAdd(&cnt[word], (rz & 1u) ? 0x10000u : 1u);
                } else {
                    int bin = (ix * GRIDSZ + iy) * GRIDSZ + iz;
                    atomicAdd(&outb[bin], 1.0f);
                }
            }
        }
    }
    __syncthreads();

    unsigned* __restrict__ slot = partials + (size_t)bx * WORDS;
    for (int w = threadIdx.x; w < WORDS; w += HTHREADS) slot[w] = cnt[w];
}

// Sum the 32 per-chunk partials per batch; plain stores (outliers never touch
// central bins; out was memset to 0).
__global__ void reduce_kernel(const unsigned* __restrict__ partials,
                              float* __restrict__ out) {
    const int b = blockIdx.y;
    const int w = blockIdx.x * 256 + threadIdx.x;   // [0, WORDS)
    const unsigned* __restrict__ base = partials + (size_t)b * CHUNKS * WORDS;
    unsigned s0 = 0, s1 = 0;
#pragma unroll 4
    for (int c = 0; c < CHUNKS; ++c) {
        unsigned v = base[(size_t)c * WORDS + w];
        s0 += v & 0xFFFFu;
        s1 += v >> 16;
    }
    int ix = R0 + (w >> 9);
    int iy = R0 + ((w >> 4) & (RSZ - 1));
    int iz = R0 + ((w & (RSZ / 2 - 1)) << 1);
    float* __restrict__ outb = out + (size_t)b * BINS_PER_BATCH;
    int bin = (ix * GRIDSZ + iy) * GRIDSZ + iz;
    outb[bin]     = (float)s0;
    outb[bin + 1] = (float)s1;
}

// Fallback (ws too small for hist partials): direct-atomic hist.
__global__ void hist_kernel(const float* __restrict__ pts,
                            const float* __restrict__ finals,
                            float* __restrict__ out) {
    const int b = blockIdx.y;
    const float mn0 = finals[b * 8 + 0], mn1 = finals[b * 8 + 1], mn2 = finals[b * 8 + 2];
    const float d0  = finals[b * 8 + 3], d1  = finals[b * 8 + 4], d2  = finals[b * 8 + 5];

    const float4* __restrict__ p4 =
        reinterpret_cast<const float4*>(pts + (size_t)b * FLOATS_PER_BATCH);
    float* __restrict__ outb = out + (size_t)b * BINS_PER_BATCH;

    const int stride = gridDim.x * blockDim.x;
    for (int i = blockIdx.x * blockDim.x + threadIdx.x; i < NTRIP; i += stride) {
        float4 A = p4[3 * i + 0];
        float4 B = p4[3 * i + 1];
        float4 C = p4[3 * i + 2];
        float xs[4] = {A.x, A.w, B.z, C.y};
        float ys[4] = {A.y, B.x, B.w, C.z};
        float zs[4] = {A.z, B.y, C.x, C.w};
#pragma unroll
        for (int j = 0; j < 4; ++j) {
            bool ok; int ix, iy, iz;
            bin_point(xs[j], ys[j], zs[j], mn0, mn1, mn2, d0, d1, d2, ok, ix, iy, iz);
            if (ok) {
                int bin = (ix * GRIDSZ + iy) * GRIDSZ + iz;
                atomicAdd(&outb[bin], 1.0f);
            }
        }
    }
}

extern "C" void kernel_launch(void* const* d_in, const int* in_sizes, int n_in,
                              void* d_out, int out_size, void* d_ws, size_t ws_size,
                              hipStream_t stream) {
    const float* pts = (const float*)d_in[0];
    float* out = (float*)d_out;
    unsigned* ws = (unsigned*)d_ws;

    float* finals = (float*)(ws + FINAL_OFF);
    float* mm_partials = (float*)(ws + PART_OFF_U32);   // reused region
    unsigned* hist_partials = ws + PART_OFF_U32;

    const size_t need = (size_t)PART_OFF_U32 * 4 + (size_t)HBLOCKS * WORDS * 4;

    hipMemsetAsync(d_out, 0, (size_t)out_size * sizeof(float), stream);
    minmax_stage1<<<dim3(MMBLK, NBATCH), 256, 0, stream>>>(pts, mm_partials);
    minmax_stage2<<<NBATCH, MMBLK, 0, stream>>>(mm_partials, finals);

    if (ws_size >= need) {
        hist_lds_kernel<<<HBLOCKS, HTHREADS, 0, stream>>>(pts, finals, hist_partials, out);
        reduce_kernel<<<dim3(WORDS / 256, NBATCH), 256, 0, stream>>>(hist_partials, out);
    } else {
        hist_kernel<<<dim3(128, NBATCH), 256, 0, stream>>>(pts, finals, out);
    }
}

// Round 9
// 72.359 us; speedup vs baseline: 7.5993x; 1.0529x over previous
//
#include <hip/hip_runtime.h>

#define GRIDSZ 64
#define NBATCH 16
#define NPTS   500000
#define NTRIP  (NPTS / 4)          // 125000 triples-of-float4 (4 points each)
#define FLOATS_PER_BATCH (NPTS * 3)
#define BINS_PER_BATCH (GRIDSZ * GRIDSZ * GRIDSZ)
#define OUT_FLOAT4 (NBATCH * BINS_PER_BATCH / 4)   // 1048576 float4s in d_out

// LDS-privatized histogram parameters
#define CHUNKS   32                 // blocks per batch in hist pass
#define HBLOCKS  (NBATCH * CHUNKS)  // 512 blocks (2 per CU with 64KB LDS)
#define HTHREADS 512
#define R0  16                      // central region = bins [16,48) per dim
#define RSZ 32
#define WORDS (RSZ * RSZ * (RSZ / 2))  // 16384 packed u16-pair words = 64KB

// minmax config
#define MMBLK 128                   // stage-1 blocks per batch
#define MMTOTTHREADS (MMBLK * NBATCH * 256)   // 524288

// ws layout (u32 units):
//  [0 .. 127]   finals: per batch 8 floats {mn0,mn1,mn2,den0,den1,den2,pad,pad}
//  [128..255]   pad
//  [256 .. ]    hist partials (HBLOCKS*WORDS u32) — ALSO reused (earlier in the
//               timeline) as minmax stage-1 partials (NBATCH*MMBLK*8 floats)
#define FINAL_OFF 0
#define PART_OFF_U32 256

// Stage 1 also zeroes d_out (replaces hipMemsetAsync: the runtime's
// fillBufferAligned ran at ~300 GB/s / 55 us for 16 MB — round-7 profile).
// Stream ordering mm1 -> mm2 -> hist makes the zeros visible to hist atomics.
__global__ __launch_bounds__(256) void minmax_stage1(
        const float* __restrict__ pts, float* __restrict__ partials,
        float4* __restrict__ out4) {
    const int b = blockIdx.y;
    const int linBlk = b * MMBLK + blockIdx.x;          // 0..2047
    const int linTid = linBlk * 256 + threadIdx.x;      // 0..524287

    // zero d_out: 2 float4 per thread, fully coalesced
    const float4 z = make_float4(0.f, 0.f, 0.f, 0.f);
    out4[linTid] = z;
    out4[linTid + MMTOTTHREADS] = z;

    const float4* __restrict__ p4 =
        reinterpret_cast<const float4*>(pts + (size_t)b * FLOATS_PER_BATCH);

    float mn[3] = {INFINITY, INFINITY, INFINITY};
    float mx[3] = {-INFINITY, -INFINITY, -INFINITY};

    const int stride = MMBLK * 256;
    for (int i = blockIdx.x * 256 + threadIdx.x; i < NTRIP; i += stride) {
        float4 A = p4[3 * i + 0];
        float4 B = p4[3 * i + 1];
        float4 C = p4[3 * i + 2];
        // 4 points: (A.x,A.y,A.z) (A.w,B.x,B.y) (B.z,B.w,C.x) (C.y,C.z,C.w)
        float xs[4] = {A.x, A.w, B.z, C.y};
        float ys[4] = {A.y, B.x, B.w, C.z};
        float zs[4] = {A.z, B.y, C.x, C.w};
#pragma unroll
        for (int j = 0; j < 4; ++j) {
            mn[0] = fminf(mn[0], xs[j]); mx[0] = fmaxf(mx[0], xs[j]);
            mn[1] = fminf(mn[1], ys[j]); mx[1] = fmaxf(mx[1], ys[j]);
            mn[2] = fminf(mn[2], zs[j]); mx[2] = fmaxf(mx[2], zs[j]);
        }
    }
    // wave-64 butterfly
#pragma unroll
    for (int m = 1; m < 64; m <<= 1) {
#pragma unroll
        for (int c = 0; c < 3; ++c) {
            mn[c] = fminf(mn[c], __shfl_xor(mn[c], m));
            mx[c] = fmaxf(mx[c], __shfl_xor(mx[c], m));
        }
    }
    // cross-wave via LDS (4 waves)
    __shared__ float red[4][6];
    const int wave = threadIdx.x >> 6;
    if ((threadIdx.x & 63) == 0) {
        red[wave][0] = mn[0]; red[wave][1] = mn[1]; red[wave][2] = mn[2];
        red[wave][3] = mx[0]; red[wave][4] = mx[1]; red[wave][5] = mx[2];
    }
    __syncthreads();
    if (threadIdx.x == 0) {
#pragma unroll
        for (int w = 1; w < 4; ++w) {
#pragma unroll
            for (int c = 0; c < 3; ++c) {
                red[0][c]     = fminf(red[0][c],     red[w][c]);
                red[0][3 + c] = fmaxf(red[0][3 + c], red[w][3 + c]);
            }
        }
        float4* slot = reinterpret_cast<float4*>(partials + (size_t)linBlk * 8);
        slot[0] = make_float4(red[0][0], red[0][1], red[0][2], red[0][3]);
        slot[1] = make_float4(red[0][4], red[0][5], 0.0f, 0.0f);
    }
}

// One block per batch: reduce MMBLK partials -> finals {mn[3], den[3]}
__global__ __launch_bounds__(MMBLK) void minmax_stage2(
        const float* __restrict__ partials, float* __restrict__ finals) {
    const int b = blockIdx.x;
    const float4* slot = reinterpret_cast<const float4*>(
        partials + (size_t)(b * MMBLK + threadIdx.x) * 8);
    float4 a = slot[0];
    float4 c = slot[1];
    float mn[3] = {a.x, a.y, a.z};
    float mx[3] = {a.w, c.x, c.y};
#pragma unroll
    for (int m = 1; m < 64; m <<= 1) {
#pragma unroll
        for (int k = 0; k < 3; ++k) {
            mn[k] = fminf(mn[k], __shfl_xor(mn[k], m));
            mx[k] = fmaxf(mx[k], __shfl_xor(mx[k], m));
        }
    }
    __shared__ float red[2][6];
    const int wave = threadIdx.x >> 6;
    if ((threadIdx.x & 63) == 0) {
        red[wave][0] = mn[0]; red[wave][1] = mn[1]; red[wave][2] = mn[2];
        red[wave][3] = mx[0]; red[wave][4] = mx[1]; red[wave][5] = mx[2];
    }
    __syncthreads();
    if (threadIdx.x == 0) {
        float* f = finals + b * 8;
#pragma unroll
        for (int k = 0; k < 3; ++k) {
            float lo = fminf(red[0][k],     red[1][k]);
            float hi = fmaxf(red[0][3 + k], red[1][3 + k]);
            f[k]     = lo;
            f[3 + k] = (hi - lo) + 1e-6f;   // matches ref: (pmax-pmin)+EPS
        }
        f[6] = 0.0f; f[7] = 0.0f;
    }
}

// Shared binning math — EXACTLY the arithmetic of the passing rounds.
__device__ __forceinline__ void bin_point(float x, float y, float z,
                                          float mn0, float mn1, float mn2,
                                          float d0, float d1, float d2,
                                          bool& ok, int& ix, int& iy, int& iz) {
    float tx = (x - mn0) / d0;
    float ty = (y - mn1) / d1;
    float tz = (z - mn2) / d2;
    float nx = tx * 2.0f - 1.0f;
    float ny = ty * 2.0f - 1.0f;
    float nz = tz * 2.0f - 1.0f;
    ok = (nx >= -1.0f) & (nx <= 1.0f) &
         (ny >= -1.0f) & (ny <= 1.0f) &
         (nz >= -1.0f) & (nz <= 1.0f);
    ix = (int)floorf((nx + 1.0f) * 32.0f);
    iy = (int)floorf((ny + 1.0f) * 32.0f);
    iz = (int)floorf((nz + 1.0f) * 32.0f);
    ix = min(max(ix, 0), GRIDSZ - 1);
    iy = min(max(iy, 0), GRIDSZ - 1);
    iz = min(max(iz, 0), GRIDSZ - 1);
}

// LDS-privatized hist: central 32^3 bins counted in LDS (packed 2xu16),
// outliers via global atomics, partials flushed to ws with plain stores.
__global__ __launch_bounds__(HTHREADS) void hist_lds_kernel(
        const float* __restrict__ pts, const float* __restrict__ finals,
        unsigned* __restrict__ partials, float* __restrict__ out) {
    __shared__ unsigned cnt[WORDS];          // 64 KB
    const int bx = blockIdx.x;
    const int b = bx >> 5;                   // batch
    const int chunk = bx & (CHUNKS - 1);

    for (int w = threadIdx.x; w < WORDS; w += HTHREADS) cnt[w] = 0u;
    __syncthreads();

    const float mn0 = finals[b * 8 + 0], mn1 = finals[b * 8 + 1], mn2 = finals[b * 8 + 2];
    const float d0  = finals[b * 8 + 3], d1  = finals[b * 8 + 4], d2  = finals[b * 8 + 5];

    const float4* __restrict__ p4 =
        reinterpret_cast<const float4*>(pts + (size_t)b * FLOATS_PER_BATCH);
    float* __restrict__ outb = out + (size_t)b * BINS_PER_BATCH;

    for (int i = chunk * HTHREADS + threadIdx.x; i < NTRIP; i += CHUNKS * HTHREADS) {
        float4 A = p4[3 * i + 0];
        float4 B = p4[3 * i + 1];
        float4 C = p4[3 * i + 2];
        float xs[4] = {A.x, A.w, B.z, C.y};
        float ys[4] = {A.y, B.x, B.w, C.z};
        float zs[4] = {A.z, B.y, C.x, C.w};
#pragma unroll
        for (int j = 0; j < 4; ++j) {
            bool ok; int ix, iy, iz;
            bin_point(xs[j], ys[j], zs[j], mn0, mn1, mn2, d0, d1, d2, ok, ix, iy, iz);
            if (ok) {
                unsigned rx = (unsigned)(ix - R0), ry = (unsigned)(iy - R0), rz = (unsigned)(iz - R0);
                if ((rx < RSZ) & (ry < RSZ) & (rz < RSZ)) {
                    unsigned word = (rx * RSZ + ry) * (RSZ / 2) + (rz >> 1);
                    atomicAdd(&cnt[word], (rz & 1u) ? 0x10000u : 1u);
                } else {
                    int bin = (ix * GRIDSZ + iy) * GRIDSZ + iz;
                    atomicAdd(&outb[bin], 1.0f);
                }
            }
        }
    }
    __syncthreads();

    unsigned* __restrict__ slot = partials + (size_t)bx * WORDS;
    for (int w = threadIdx.x; w < WORDS; w += HTHREADS) slot[w] = cnt[w];
}

// Sum the 32 per-chunk partials per batch; plain stores (outliers never touch
// central bins; out was zeroed by minmax_stage1).
__global__ void reduce_kernel(const unsigned* __restrict__ partials,
                              float* __restrict__ out) {
    const int b = blockIdx.y;
    const int w = blockIdx.x * 256 + threadIdx.x;   // [0, WORDS)
    const unsigned* __restrict__ base = partials + (size_t)b * CHUNKS * WORDS;
    unsigned s0 = 0, s1 = 0;
#pragma unroll 4
    for (int c = 0; c < CHUNKS; ++c) {
        unsigned v = base[(size_t)c * WORDS + w];
        s0 += v & 0xFFFFu;
        s1 += v >> 16;
    }
    int ix = R0 + (w >> 9);
    int iy = R0 + ((w >> 4) & (RSZ - 1));
    int iz = R0 + ((w & (RSZ / 2 - 1)) << 1);
    float* __restrict__ outb = out + (size_t)b * BINS_PER_BATCH;
    int bin = (ix * GRIDSZ + iy) * GRIDSZ + iz;
    outb[bin]     = (float)s0;
    outb[bin + 1] = (float)s1;
}

// Fallback (ws too small for hist partials): direct-atomic hist.
__global__ void hist_kernel(const float* __restrict__ pts,
                            const float* __restrict__ finals,
                            float* __restrict__ out) {
    const int b = blockIdx.y;
    const float mn0 = finals[b * 8 + 0], mn1 = finals[b * 8 + 1], mn2 = finals[b * 8 + 2];
    const float d0  = finals[b * 8 + 3], d1  = finals[b * 8 + 4], d2  = finals[b * 8 + 5];

    const float4* __restrict__ p4 =
        reinterpret_cast<const float4*>(pts + (size_t)b * FLOATS_PER_BATCH);
    float* __restrict__ outb = out + (size_t)b * BINS_PER_BATCH;

    const int stride = gridDim.x * blockDim.x;
    for (int i = blockIdx.x * blockDim.x + threadIdx.x; i < NTRIP; i += stride) {
        float4 A = p4[3 * i + 0];
        float4 B = p4[3 * i + 1];
        float4 C = p4[3 * i + 2];
        float xs[4] = {A.x, A.w, B.z, C.y};
        float ys[4] = {A.y, B.x, B.w, C.z};
        float zs[4] = {A.z, B.y, C.x, C.w};
#pragma unroll
        for (int j = 0; j < 4; ++j) {
            bool ok; int ix, iy, iz;
            bin_point(xs[j], ys[j], zs[j], mn0, mn1, mn2, d0, d1, d2, ok, ix, iy, iz);
            if (ok) {
                int bin = (ix * GRIDSZ + iy) * GRIDSZ + iz;
                atomicAdd(&outb[bin], 1.0f);
            }
        }
    }
}

extern "C" void kernel_launch(void* const* d_in, const int* in_sizes, int n_in,
                              void* d_out, int out_size, void* d_ws, size_t ws_size,
                              hipStream_t stream) {
    const float* pts = (const float*)d_in[0];
    float* out = (float*)d_out;
    unsigned* ws = (unsigned*)d_ws;

    float* finals = (float*)(ws + FINAL_OFF);
    float* mm_partials = (float*)(ws + PART_OFF_U32);   // reused region
    unsigned* hist_partials = ws + PART_OFF_U32;

    const size_t need = (size_t)PART_OFF_U32 * 4 + (size_t)HBLOCKS * WORDS * 4;

    // d_out zeroing is fused into minmax_stage1 (runtime fill kernel was the
    // round-7 bottleneck: 16 MB at ~300 GB/s).
    minmax_stage1<<<dim3(MMBLK, NBATCH), 256, 0, stream>>>(
        pts, mm_partials, (float4*)out);
    minmax_stage2<<<NBATCH, MMBLK, 0, stream>>>(mm_partials, finals);

    if (ws_size >= need) {
        hist_lds_kernel<<<HBLOCKS, HTHREADS, 0, stream>>>(pts, finals, hist_partials, out);
        reduce_kernel<<<dim3(WORDS / 256, NBATCH), 256, 0, stream>>>(hist_partials, out);
    } else {
        hist_kernel<<<dim3(128, NBATCH), 256, 0, stream>>>(pts, finals, out);
    }
}

// Round 10
// 64.234 us; speedup vs baseline: 8.5606x; 1.1265x over previous
//
#include <hip/hip_runtime.h>

#define GRIDSZ 64
#define NBATCH 16
#define NPTS   500000
#define NTRIP  (NPTS / 4)          // 125000 triples-of-float4 (4 points each)
#define FLOATS_PER_BATCH (NPTS * 3)
#define BINS_PER_BATCH (GRIDSZ * GRIDSZ * GRIDSZ)

// LDS-privatized histogram parameters (u8-packed: 4 counts per u32)
#define CHUNKS   32                 // blocks per batch in hist pass
#define HBLOCKS  (NBATCH * CHUNKS)  // 512 blocks
#define HTHREADS 512
#define R0  16                      // central region = bins [16,48) per dim
#define RSZ 32
#define WORDS8 (RSZ * RSZ * (RSZ / 4))  // 8192 u32 words (4 u8 counts each) = 32KB

// minmax config
#define MMBLK 128                   // stage-1 blocks per batch
#define MMTOTTHREADS (MMBLK * NBATCH * 256)   // 524288

// ws layout (u32 units):
//  [0 .. 127]     finals (fallback path only): per batch 8 floats
//  [128 .. 255]   pad
//  [256 .. 16639] mm stage-1 partials: 2048 blocks x 8 floats = 64KB
//  [16640 .. ]    hist u8 partials: HBLOCKS x WORDS8 u32 = 16MB
#define FINAL_OFF 0
#define PART_OFF_U32 256
#define HIST_PART_OFF_U32 (PART_OFF_U32 + MMBLK * NBATCH * 8)   // 16640

// Stage 1 also zeroes d_out (runtime fillBufferAligned was ~300 GB/s for
// 16 MB — round-7 profile). Stream ordering makes zeros visible to hist.
__global__ __launch_bounds__(256) void minmax_stage1(
        const float* __restrict__ pts, float* __restrict__ partials,
        float4* __restrict__ out4) {
    const int b = blockIdx.y;
    const int linBlk = b * MMBLK + blockIdx.x;          // 0..2047
    const int linTid = linBlk * 256 + threadIdx.x;      // 0..524287

    const float4 z = make_float4(0.f, 0.f, 0.f, 0.f);
    out4[linTid] = z;
    out4[linTid + MMTOTTHREADS] = z;

    const float4* __restrict__ p4 =
        reinterpret_cast<const float4*>(pts + (size_t)b * FLOATS_PER_BATCH);

    float mn[3] = {INFINITY, INFINITY, INFINITY};
    float mx[3] = {-INFINITY, -INFINITY, -INFINITY};

    const int stride = MMBLK * 256;
    for (int i = blockIdx.x * 256 + threadIdx.x; i < NTRIP; i += stride) {
        float4 A = p4[3 * i + 0];
        float4 B = p4[3 * i + 1];
        float4 C = p4[3 * i + 2];
        // 4 points: (A.x,A.y,A.z) (A.w,B.x,B.y) (B.z,B.w,C.x) (C.y,C.z,C.w)
        float xs[4] = {A.x, A.w, B.z, C.y};
        float ys[4] = {A.y, B.x, B.w, C.z};
        float zs[4] = {A.z, B.y, C.x, C.w};
#pragma unroll
        for (int j = 0; j < 4; ++j) {
            mn[0] = fminf(mn[0], xs[j]); mx[0] = fmaxf(mx[0], xs[j]);
            mn[1] = fminf(mn[1], ys[j]); mx[1] = fmaxf(mx[1], ys[j]);
            mn[2] = fminf(mn[2], zs[j]); mx[2] = fmaxf(mx[2], zs[j]);
        }
    }
#pragma unroll
    for (int m = 1; m < 64; m <<= 1) {
#pragma unroll
        for (int c = 0; c < 3; ++c) {
            mn[c] = fminf(mn[c], __shfl_xor(mn[c], m));
            mx[c] = fmaxf(mx[c], __shfl_xor(mx[c], m));
        }
    }
    __shared__ float red[4][6];
    const int wave = threadIdx.x >> 6;
    if ((threadIdx.x & 63) == 0) {
        red[wave][0] = mn[0]; red[wave][1] = mn[1]; red[wave][2] = mn[2];
        red[wave][3] = mx[0]; red[wave][4] = mx[1]; red[wave][5] = mx[2];
    }
    __syncthreads();
    if (threadIdx.x == 0) {
#pragma unroll
        for (int w = 1; w < 4; ++w) {
#pragma unroll
            for (int c = 0; c < 3; ++c) {
                red[0][c]     = fminf(red[0][c],     red[w][c]);
                red[0][3 + c] = fmaxf(red[0][3 + c], red[w][3 + c]);
            }
        }
        float4* slot = reinterpret_cast<float4*>(partials + (size_t)linBlk * 8);
        slot[0] = make_float4(red[0][0], red[0][1], red[0][2], red[0][3]);
        slot[1] = make_float4(red[0][4], red[0][5], 0.0f, 0.0f);
    }
}

// Fallback-path only: reduce MMBLK partials -> finals {mn[3], den[3]}
__global__ __launch_bounds__(MMBLK) void minmax_stage2(
        const float* __restrict__ partials, float* __restrict__ finals) {
    const int b = blockIdx.x;
    const float4* slot = reinterpret_cast<const float4*>(
        partials + (size_t)(b * MMBLK + threadIdx.x) * 8);
    float4 a = slot[0];
    float4 c = slot[1];
    float mn[3] = {a.x, a.y, a.z};
    float mx[3] = {a.w, c.x, c.y};
#pragma unroll
    for (int m = 1; m < 64; m <<= 1) {
#pragma unroll
        for (int k = 0; k < 3; ++k) {
            mn[k] = fminf(mn[k], __shfl_xor(mn[k], m));
            mx[k] = fmaxf(mx[k], __shfl_xor(mx[k], m));
        }
    }
    __shared__ float red[2][6];
    const int wave = threadIdx.x >> 6;
    if ((threadIdx.x & 63) == 0) {
        red[wave][0] = mn[0]; red[wave][1] = mn[1]; red[wave][2] = mn[2];
        red[wave][3] = mx[0]; red[wave][4] = mx[1]; red[wave][5] = mx[2];
    }
    __syncthreads();
    if (threadIdx.x == 0) {
        float* f = finals + b * 8;
#pragma unroll
        for (int k = 0; k < 3; ++k) {
            float lo = fminf(red[0][k],     red[1][k]);
            float hi = fmaxf(red[0][3 + k], red[1][3 + k]);
            f[k]     = lo;
            f[3 + k] = (hi - lo) + 1e-6f;   // matches ref: (pmax-pmin)+EPS
        }
        f[6] = 0.0f; f[7] = 0.0f;
    }
}

// Shared binning math — EXACTLY the arithmetic of the passing rounds.
__device__ __forceinline__ void bin_point(float x, float y, float z,
                                          float mn0, float mn1, float mn2,
                                          float d0, float d1, float d2,
                                          bool& ok, int& ix, int& iy, int& iz) {
    float tx = (x - mn0) / d0;
    float ty = (y - mn1) / d1;
    float tz = (z - mn2) / d2;
    float nx = tx * 2.0f - 1.0f;
    float ny = ty * 2.0f - 1.0f;
    float nz = tz * 2.0f - 1.0f;
    ok = (nx >= -1.0f) & (nx <= 1.0f) &
         (ny >= -1.0f) & (ny <= 1.0f) &
         (nz >= -1.0f) & (nz <= 1.0f);
    ix = (int)floorf((nx + 1.0f) * 32.0f);
    iy = (int)floorf((ny + 1.0f) * 32.0f);
    iz = (int)floorf((nz + 1.0f) * 32.0f);
    ix = min(max(ix, 0), GRIDSZ - 1);
    iy = min(max(iy, 0), GRIDSZ - 1);
    iz = min(max(iz, 0), GRIDSZ - 1);
}

// u8-packed LDS hist. Each block: (1) reduce the 128 mm-partials itself
// (fmin/fmax order-invariant => bit-identical mn/den; kills the mm2 launch
// bubble), (2) count central 32^3 bins in 32KB LDS (u8 x4 per word; per-chunk
// per-bin max ~4 expected vs 255 cap), (3) flush with plain stores.
__global__ __launch_bounds__(HTHREADS) void hist_lds_kernel(
        const float* __restrict__ pts, const float* __restrict__ mm_partials,
        unsigned* __restrict__ partials, float* __restrict__ out) {
    __shared__ unsigned cnt[WORDS8];         // 32 KB
    __shared__ float fin[6];
    const int bx = blockIdx.x;
    const int b = bx >> 5;                   // batch
    const int chunk = bx & (CHUNKS - 1);

    for (int w = threadIdx.x; w < WORDS8; w += HTHREADS) cnt[w] = 0u;

    // per-block finals reduction (threads 0..127, 2 waves)
    if (threadIdx.x < MMBLK) {
        const float4* slot = reinterpret_cast<const float4*>(
            mm_partials + (size_t)(b * MMBLK + threadIdx.x) * 8);
        float4 a = slot[0];
        float4 c = slot[1];
        float mn[3] = {a.x, a.y, a.z};
        float mx[3] = {a.w, c.x, c.y};
#pragma unroll
        for (int m = 1; m < 64; m <<= 1) {
#pragma unroll
            for (int k = 0; k < 3; ++k) {
                mn[k] = fminf(mn[k], __shfl_xor(mn[k], m));
                mx[k] = fmaxf(mx[k], __shfl_xor(mx[k], m));
            }
        }
        __shared__ float red[2][6];
        const int wave = threadIdx.x >> 6;
        if ((threadIdx.x & 63) == 0) {
            red[wave][0] = mn[0]; red[wave][1] = mn[1]; red[wave][2] = mn[2];
            red[wave][3] = mx[0]; red[wave][4] = mx[1]; red[wave][5] = mx[2];
        }
        __syncthreads();
        if (threadIdx.x == 0) {
#pragma unroll
            for (int k = 0; k < 3; ++k) {
                float lo = fminf(red[0][k],     red[1][k]);
                float hi = fmaxf(red[0][3 + k], red[1][3 + k]);
                fin[k]     = lo;
                fin[3 + k] = (hi - lo) + 1e-6f;   // matches ref
            }
        }
    } else {
        __syncthreads();   // matching barrier for threads >= 128
    }
    __syncthreads();

    const float mn0 = fin[0], mn1 = fin[1], mn2 = fin[2];
    const float d0 = fin[3], d1 = fin[4], d2 = fin[5];

    const float4* __restrict__ p4 =
        reinterpret_cast<const float4*>(pts + (size_t)b * FLOATS_PER_BATCH);
    float* __restrict__ outb = out + (size_t)b * BINS_PER_BATCH;

    for (int i = chunk * HTHREADS + threadIdx.x; i < NTRIP; i += CHUNKS * HTHREADS) {
        float4 A = p4[3 * i + 0];
        float4 B = p4[3 * i + 1];
        float4 C = p4[3 * i + 2];
        float xs[4] = {A.x, A.w, B.z, C.y};
        float ys[4] = {A.y, B.x, B.w, C.z};
        float zs[4] = {A.z, B.y, C.x, C.w};
#pragma unroll
        for (int j = 0; j < 4; ++j) {
            bool ok; int ix, iy, iz;
            bin_point(xs[j], ys[j], zs[j], mn0, mn1, mn2, d0, d1, d2, ok, ix, iy, iz);
            if (ok) {
                unsigned rx = (unsigned)(ix - R0), ry = (unsigned)(iy - R0), rz = (unsigned)(iz - R0);
                if ((rx < RSZ) & (ry < RSZ) & (rz < RSZ)) {
                    unsigned word = (rx * RSZ + ry) * (RSZ / 4) + (rz >> 2);
                    atomicAdd(&cnt[word], 1u << ((rz & 3u) * 8u));
                } else {
                    int bin = (ix * GRIDSZ + iy) * GRIDSZ + iz;
                    atomicAdd(&outb[bin], 1.0f);
                }
            }
        }
    }
    __syncthreads();

    unsigned* __restrict__ slot = partials + (size_t)bx * WORDS8;
    for (int w = threadIdx.x; w < WORDS8; w += HTHREADS) slot[w] = cnt[w];
}

// Sum the 32 per-chunk u8 partials per batch; coalesced float4 stores
// (outliers never touch central bins; out zeroed by minmax_stage1).
__global__ void reduce_kernel(const unsigned* __restrict__ partials,
                              float* __restrict__ out) {
    const int b = blockIdx.y;
    const int w = blockIdx.x * 256 + threadIdx.x;   // [0, WORDS8)
    const unsigned* __restrict__ base = partials + (size_t)b * CHUNKS * WORDS8;
    unsigned s0 = 0, s1 = 0, s2 = 0, s3 = 0;
#pragma unroll 4
    for (int c = 0; c < CHUNKS; ++c) {
        unsigned v = base[(size_t)c * WORDS8 + w];
        s0 += v & 0xFFu;
        s1 += (v >> 8) & 0xFFu;
        s2 += (v >> 16) & 0xFFu;
        s3 += v >> 24;
    }
    int ix = R0 + (w >> 8);                  // w / (RSZ * RSZ/4)
    int iy = R0 + ((w >> 3) & (RSZ - 1));
    int iz = R0 + ((w & (RSZ / 4 - 1)) << 2);
    float* __restrict__ outb = out + (size_t)b * BINS_PER_BATCH;
    int bin = (ix * GRIDSZ + iy) * GRIDSZ + iz;
    *reinterpret_cast<float4*>(&outb[bin]) =
        make_float4((float)s0, (float)s1, (float)s2, (float)s3);
}

// Fallback (ws too small): direct-atomic hist using finals from mm2.
__global__ void hist_kernel(const float* __restrict__ pts,
                            const float* __restrict__ finals,
                            float* __restrict__ out) {
    const int b = blockIdx.y;
    const float mn0 = finals[b * 8 + 0], mn1 = finals[b * 8 + 1], mn2 = finals[b * 8 + 2];
    const float d0  = finals[b * 8 + 3], d1  = finals[b * 8 + 4], d2  = finals[b * 8 + 5];

    const float4* __restrict__ p4 =
        reinterpret_cast<const float4*>(pts + (size_t)b * FLOATS_PER_BATCH);
    float* __restrict__ outb = out + (size_t)b * BINS_PER_BATCH;

    const int stride = gridDim.x * blockDim.x;
    for (int i = blockIdx.x * blockDim.x + threadIdx.x; i < NTRIP; i += stride) {
        float4 A = p4[3 * i + 0];
        float4 B = p4[3 * i + 1];
        float4 C = p4[3 * i + 2];
        float xs[4] = {A.x, A.w, B.z, C.y};
        float ys[4] = {A.y, B.x, B.w, C.z};
        float zs[4] = {A.z, B.y, C.x, C.w};
#pragma unroll
        for (int j = 0; j < 4; ++j) {
            bool ok; int ix, iy, iz;
            bin_point(xs[j], ys[j], zs[j], mn0, mn1, mn2, d0, d1, d2, ok, ix, iy, iz);
            if (ok) {
                int bin = (ix * GRIDSZ + iy) * GRIDSZ + iz;
                atomicAdd(&outb[bin], 1.0f);
            }
        }
    }
}

extern "C" void kernel_launch(void* const* d_in, const int* in_sizes, int n_in,
                              void* d_out, int out_size, void* d_ws, size_t ws_size,
                              hipStream_t stream) {
    const float* pts = (const float*)d_in[0];
    float* out = (float*)d_out;
    unsigned* ws = (unsigned*)d_ws;

    float* finals = (float*)(ws + FINAL_OFF);
    float* mm_partials = (float*)(ws + PART_OFF_U32);
    unsigned* hist_partials = ws + HIST_PART_OFF_U32;

    const size_t need = ((size_t)HIST_PART_OFF_U32 + (size_t)HBLOCKS * WORDS8) * 4;

    minmax_stage1<<<dim3(MMBLK, NBATCH), 256, 0, stream>>>(
        pts, mm_partials, (float4*)out);

    if (ws_size >= need) {
        hist_lds_kernel<<<HBLOCKS, HTHREADS, 0, stream>>>(
            pts, mm_partials, hist_partials, out);
        reduce_kernel<<<dim3(WORDS8 / 256, NBATCH), 256, 0, stream>>>(
            hist_partials, out);
    } else {
        minmax_stage2<<<NBATCH, MMBLK, 0, stream>>>(mm_partials, finals);
        hist_kernel<<<dim3(128, NBATCH), 256, 0, stream>>>(pts, finals, out);
    }
}